// Round 3
// baseline (792.233 us; speedup 1.0000x reference)
//
#include <hip/hip_runtime.h>
#include <hip/hip_bf16.h>

#define N_NODES 50000
#define N_EDGES 400000
#define D 16
#define HID 64
#define NDEG (N_NODES)
#define NACC (N_NODES * D)
#define FLAGS_OFF (NDEG + NACC)   // float-index of 2 int flags in ws

// ---------------------------------------------------------------------------
// dtype helpers — harness may hand us bf16 or fp32 floats, int32 or int64
// indices. Detect from data device-side (branch-uniform, ~free).
// ---------------------------------------------------------------------------
__device__ __forceinline__ float bf_bits(unsigned short us) {
    return __uint_as_float(((unsigned)us) << 16);
}

__device__ __forceinline__ float ld_f(const void* p, int idx, int f32) {
    return f32 ? ((const float*)p)[idx]
               : bf_bits(((const unsigned short*)p)[idx]);
}

// Load 16 consecutive values -> 16 floats (vectorized both paths)
__device__ __forceinline__ void load16(const void* __restrict__ p, long long base,
                                       int f32, float* o) {
    if (f32) {
        const float4* q = (const float4*)((const float*)p + base);
        float4 a = q[0], b = q[1], c = q[2], d = q[3];
        o[0]=a.x; o[1]=a.y; o[2]=a.z; o[3]=a.w;
        o[4]=b.x; o[5]=b.y; o[6]=b.z; o[7]=b.w;
        o[8]=c.x; o[9]=c.y; o[10]=c.z; o[11]=c.w;
        o[12]=d.x; o[13]=d.y; o[14]=d.z; o[15]=d.w;
    } else {
        const uint4* q = (const uint4*)((const unsigned short*)p + base);
        uint4 a = q[0], b = q[1];
        unsigned u[8] = {a.x, a.y, a.z, a.w, b.x, b.y, b.z, b.w};
#pragma unroll
        for (int k = 0; k < 8; k++) {
            o[2 * k]     = __uint_as_float(u[k] << 16);
            o[2 * k + 1] = __uint_as_float(u[k] & 0xffff0000u);
        }
    }
}

__device__ __forceinline__ void load_edge(const void* __restrict__ ei, int e, int is64,
                                          int& s, int& d) {
    if (is64) {
        const long long* p = (const long long*)ei;
        s = (int)p[e];
        d = (int)p[N_EDGES + e];
    } else {
        const int* p = (const int*)ei;
        s = p[e];
        d = p[N_EDGES + e];
    }
}

// ---------------------------------------------------------------------------
// Kernel 0: zero deg+acc; block 0 thread 0 writes the two dtype flags.
// ---------------------------------------------------------------------------
__global__ void init_kernel(float* __restrict__ ws,
                            const void* __restrict__ x,
                            const void* __restrict__ ei) {
    int i = blockIdx.x * blockDim.x + threadIdx.x;
    if (i < FLAGS_OFF) ws[i] = 0.0f;
    if (blockIdx.x == 0 && threadIdx.x == 0) {
        // x stored fp32? then odd uint16s are raw mantissa bits -> wild bf16s.
        const unsigned short* h = (const unsigned short*)x;
        int f32 = 0;
        for (int k = 0; k < 256; k++) {
            float v = bf_bits(h[k]);
            if (!(v == v) || fabsf(v) > 1.0e6f) { f32 = 1; break; }
        }
        // ei stored int64? then int64-reads of genuine indices are < N_NODES;
        // int32 storage gives lo + hi*2^32 with hi a random index.
        const long long* p = (const long long*)ei;
        int i64 = 1;
        for (int k = 0; k < 16; k++) {
            long long v = p[k];
            if (v < 0 || v >= N_NODES) { i64 = 0; break; }
        }
        int* flags = (int*)(ws + FLAGS_OFF);
        flags[0] = f32;
        flags[1] = i64;
    }
}

// ---------------------------------------------------------------------------
// Kernel 1: degree count (both endpoints of every edge contribute 1)
// ---------------------------------------------------------------------------
__global__ void deg_kernel(const void* __restrict__ ei, float* __restrict__ ws) {
    const int* flags = (const int*)(ws + FLAGS_OFF);
    int i64 = flags[1];
    int e = blockIdx.x * blockDim.x + threadIdx.x;
    if (e >= N_EDGES) return;
    int s, d;
    load_edge(ei, e, i64, s, d);
    atomicAdd(&ws[s], 1.0f);   // deg = ws[0 .. N_NODES)
    atomicAdd(&ws[d], 1.0f);
}

// ---------------------------------------------------------------------------
// Kernel 2: per-edge fused MLP -> Householder -> message scatter
//   acc[s] += coef * Hs(Hd(xd)) ;  acc[d] += coef * Hd(Hs(xs))
// ---------------------------------------------------------------------------
__global__ __launch_bounds__(256) void edge_kernel(
    const void* __restrict__ x,
    const void* __restrict__ ei,
    const void* __restrict__ W1,   // [64][32] row-major
    const void* __restrict__ b1,   // [64]
    const void* __restrict__ W2,   // [16][64] row-major
    const void* __restrict__ b2,   // [16]
    float* __restrict__ ws)
{
    __shared__ __align__(16) float sW1[HID * 2 * D];  // [j][k], row j contiguous (32)
    __shared__ __align__(16) float sW2t[HID * D];     // [j][i] = W2[i][j]
    __shared__ float sb1[HID];
    __shared__ float sb2[D];
    __shared__ int sflags[2];

    const float* deg = ws;
    float* acc = ws + NDEG;
    const int* flags = (const int*)(ws + FLAGS_OFF);

    int t = threadIdx.x;
    if (t < 2) sflags[t] = flags[t];
    __syncthreads();                 // sflags visible for staging loads
    int f32 = sflags[0];

    for (int idx = t; idx < HID * 2 * D; idx += blockDim.x)
        sW1[idx] = ld_f(W1, idx, f32);
    for (int idx = t; idx < HID * D; idx += blockDim.x) {
        int j = idx / D, i = idx % D;
        sW2t[idx] = ld_f(W2, i * HID + j, f32);
    }
    if (t < HID) sb1[t] = ld_f(b1, t, f32);
    if (t < D)  sb2[t] = ld_f(b2, t, f32);
    __syncthreads();

    int e = blockIdx.x * blockDim.x + t;
    if (e >= N_EDGES) return;

    int s, d;
    load_edge(ei, e, sflags[1], s, d);

    float xs[D], xd[D];
    load16(x, (long long)s * D, f32, xs);
    load16(x, (long long)d * D, f32, xd);

    // v_s = MLP([xs,xd]), v_d = MLP([xd,xs]); joint so each W1 row is used 2x.
    float vs[D], vd[D];
#pragma unroll
    for (int i = 0; i < D; i++) { vs[i] = sb2[i]; vd[i] = sb2[i]; }

#pragma unroll 4
    for (int j = 0; j < HID; j++) {
        float hs = sb1[j], hd = sb1[j];
        const float* w = &sW1[j * 2 * D];
#pragma unroll
        for (int k = 0; k < D; k++) {
            float w0 = w[k];
            float w1 = w[D + k];
            hs = fmaf(w0, xs[k], hs);
            hs = fmaf(w1, xd[k], hs);
            hd = fmaf(w0, xd[k], hd);
            hd = fmaf(w1, xs[k], hd);
        }
        hs = fmaxf(hs, 0.0f);
        hd = fmaxf(hd, 0.0f);
        const float* w2 = &sW2t[j * D];
#pragma unroll
        for (int i = 0; i < D; i++) {
            vs[i] = fmaf(w2[i], hs, vs[i]);
            vd[i] = fmaf(w2[i], hd, vd[i]);
        }
    }

    // normalize: v / max(||v||, 1e-12)
    float ns = 0.0f, nd = 0.0f;
#pragma unroll
    for (int i = 0; i < D; i++) { ns = fmaf(vs[i], vs[i], ns); nd = fmaf(vd[i], vd[i], nd); }
    float is_ = 1.0f / fmaxf(sqrtf(ns), 1e-12f);
    float id_ = 1.0f / fmaxf(sqrtf(nd), 1e-12f);
#pragma unroll
    for (int i = 0; i < D; i++) { vs[i] *= is_; vd[i] *= id_; }

    float coef = (1.0f / sqrtf(fmaxf(deg[s], 1e-5f))) * (1.0f / sqrtf(fmaxf(deg[d], 1e-5f)));

    // H(y) = y - 2 (v.y) v ; msg->src = Hs(Hd(xd)), msg->dst = Hd(Hs(xs))
    float dot1 = 0.0f;
#pragma unroll
    for (int i = 0; i < D; i++) dot1 = fmaf(vd[i], xd[i], dot1);
    float tvec[D];
#pragma unroll
    for (int i = 0; i < D; i++) tvec[i] = fmaf(-2.0f * dot1, vd[i], xd[i]);
    float dot2 = 0.0f;
#pragma unroll
    for (int i = 0; i < D; i++) dot2 = fmaf(vs[i], tvec[i], dot2);
#pragma unroll
    for (int i = 0; i < D; i++) tvec[i] = fmaf(-2.0f * dot2, vs[i], tvec[i]);
#pragma unroll
    for (int i = 0; i < D; i++)
        atomicAdd(&acc[(long long)s * D + i], coef * tvec[i]);

    float dot3 = 0.0f;
#pragma unroll
    for (int i = 0; i < D; i++) dot3 = fmaf(vs[i], xs[i], dot3);
    float uvec[D];
#pragma unroll
    for (int i = 0; i < D; i++) uvec[i] = fmaf(-2.0f * dot3, vs[i], xs[i]);
    float dot4 = 0.0f;
#pragma unroll
    for (int i = 0; i < D; i++) dot4 = fmaf(vd[i], uvec[i], dot4);
#pragma unroll
    for (int i = 0; i < D; i++) uvec[i] = fmaf(-2.0f * dot4, vd[i], uvec[i]);
#pragma unroll
    for (int i = 0; i < D; i++)
        atomicAdd(&acc[(long long)d * D + i], coef * uvec[i]);
}

// ---------------------------------------------------------------------------
// Kernel 3: out = relu(x + acc), same dtype as x
// ---------------------------------------------------------------------------
__global__ void finalize_kernel(const void* __restrict__ x,
                                const float* __restrict__ ws,
                                void* __restrict__ out)
{
    const int* flags = (const int*)(ws + FLAGS_OFF);
    int f32 = flags[0];
    const float* acc = ws + NDEG;
    int i = blockIdx.x * blockDim.x + threadIdx.x;
    if (i >= NACC) return;
    float v = ld_f(x, i, f32) + acc[i];
    v = fmaxf(v, 0.0f);
    if (f32) ((float*)out)[i] = v;
    else     ((__hip_bfloat16*)out)[i] = __float2bfloat16(v);
}

// ---------------------------------------------------------------------------
extern "C" void kernel_launch(void* const* d_in, const int* in_sizes, int n_in,
                              void* d_out, int out_size, void* d_ws, size_t ws_size,
                              hipStream_t stream)
{
    const void* x  = d_in[0];
    const void* ei = d_in[1];
    const void* W1 = d_in[2];
    const void* b1 = d_in[3];
    const void* W2 = d_in[4];
    const void* b2 = d_in[5];

    float* ws = (float*)d_ws;   // [deg: N][acc: N*16][flags: 2 ints]

    int blk = 256;
    init_kernel<<<(FLAGS_OFF + blk - 1) / blk, blk, 0, stream>>>(ws, x, ei);
    deg_kernel<<<(N_EDGES + blk - 1) / blk, blk, 0, stream>>>(ei, ws);
    edge_kernel<<<(N_EDGES + blk - 1) / blk, blk, 0, stream>>>(x, ei, W1, b1, W2, b2, ws);
    finalize_kernel<<<(NACC + blk - 1) / blk, blk, 0, stream>>>(x, ws, d_out);
}

// Round 4
// 365.068 us; speedup vs baseline: 2.1701x; 2.1701x over previous
//
#include <hip/hip_runtime.h>
#include <hip/hip_bf16.h>

#define N_NODES 50000
#define N_EDGES 400000
#define D 16
#define HID 64

// ---------------- int-indexed workspace layout (CSR path) ----------------
#define CNT_OFF   0                               // [N] int degree counts
#define OFF_OFF   (N_NODES)                       // [N+1] int CSR offsets
#define CUR_OFF   (2 * N_NODES + 2)               // [N] int fill cursors
#define ITEMS_OFF (3 * N_NODES + 2)               // [2E] int msg-block ids
#define FLAGS_I   (3 * N_NODES + 2 + 2 * N_EDGES) // [2] int dtype flags
#define MSG_OFF   (FLAGS_I + 2)                   // [2E*16] float msgs (16B-aligned)
#define CSR_NEEDED_BYTES ((size_t)(MSG_OFF + 2 * N_EDGES * D) * 4 + 64)

// ---------------- fallback (atomic) layout ----------------
#define FB_NDEG   (N_NODES)
#define FB_NACC   (N_NODES * D)
#define FB_FLAGS  (FB_NDEG + FB_NACC)

// ---------------------------------------------------------------------------
// dtype helpers — harness may hand us bf16 or fp32 floats, int32 or int64
// indices. Detect from data device-side (branch-uniform, ~free).
// ---------------------------------------------------------------------------
__device__ __forceinline__ float bf_bits(unsigned short us) {
    return __uint_as_float(((unsigned)us) << 16);
}

__device__ __forceinline__ float ld_f(const void* p, int idx, int f32) {
    return f32 ? ((const float*)p)[idx]
               : bf_bits(((const unsigned short*)p)[idx]);
}

__device__ __forceinline__ void load16(const void* __restrict__ p, long long base,
                                       int f32, float* o) {
    if (f32) {
        const float4* q = (const float4*)((const float*)p + base);
        float4 a = q[0], b = q[1], c = q[2], d = q[3];
        o[0]=a.x; o[1]=a.y; o[2]=a.z; o[3]=a.w;
        o[4]=b.x; o[5]=b.y; o[6]=b.z; o[7]=b.w;
        o[8]=c.x; o[9]=c.y; o[10]=c.z; o[11]=c.w;
        o[12]=d.x; o[13]=d.y; o[14]=d.z; o[15]=d.w;
    } else {
        const uint4* q = (const uint4*)((const unsigned short*)p + base);
        uint4 a = q[0], b = q[1];
        unsigned u[8] = {a.x, a.y, a.z, a.w, b.x, b.y, b.z, b.w};
#pragma unroll
        for (int k = 0; k < 8; k++) {
            o[2 * k]     = __uint_as_float(u[k] << 16);
            o[2 * k + 1] = __uint_as_float(u[k] & 0xffff0000u);
        }
    }
}

__device__ __forceinline__ void load_edge(const void* __restrict__ ei, int e, int is64,
                                          int& s, int& d) {
    if (is64) {
        const long long* p = (const long long*)ei;
        s = (int)p[e];
        d = (int)p[N_EDGES + e];
    } else {
        const int* p = (const int*)ei;
        s = p[e];
        d = p[N_EDGES + e];
    }
}

__device__ __forceinline__ void detect_flags(const void* x, const void* ei, int* flags) {
    const unsigned short* h = (const unsigned short*)x;
    int f32 = 0;
    for (int k = 0; k < 256; k++) {
        float v = bf_bits(h[k]);
        if (!(v == v) || fabsf(v) > 1.0e6f) { f32 = 1; break; }
    }
    const long long* p = (const long long*)ei;
    int i64 = 1;
    for (int k = 0; k < 16; k++) {
        long long v = p[k];
        if (v < 0 || v >= N_NODES) { i64 = 0; break; }
    }
    flags[0] = f32;
    flags[1] = i64;
}

// ---------------------------------------------------------------------------
// Shared per-edge math: given xs, xd, coef and staged weights, produce
//   ms = coef * Hs(Hd(xd))   (message to src)
//   md = coef * Hd(Hs(xs))   (message to dst)
// ---------------------------------------------------------------------------
__device__ __forceinline__ void edge_math(
    const float* __restrict__ sW1, const float* __restrict__ sW2t,
    const float* __restrict__ sb1, const float* __restrict__ sb2,
    const float* xs, const float* xd, float coef,
    float* ms, float* md)
{
    float vs[D], vd[D];
#pragma unroll
    for (int i = 0; i < D; i++) { vs[i] = sb2[i]; vd[i] = sb2[i]; }

#pragma unroll 4
    for (int j = 0; j < HID; j++) {
        float hs = sb1[j], hd = sb1[j];
        const float* w = &sW1[j * 2 * D];
#pragma unroll
        for (int k = 0; k < D; k++) {
            float w0 = w[k];
            float w1 = w[D + k];
            hs = fmaf(w0, xs[k], hs);
            hs = fmaf(w1, xd[k], hs);
            hd = fmaf(w0, xd[k], hd);
            hd = fmaf(w1, xs[k], hd);
        }
        hs = fmaxf(hs, 0.0f);
        hd = fmaxf(hd, 0.0f);
        const float* w2 = &sW2t[j * D];
#pragma unroll
        for (int i = 0; i < D; i++) {
            vs[i] = fmaf(w2[i], hs, vs[i]);
            vd[i] = fmaf(w2[i], hd, vd[i]);
        }
    }

    float ns = 0.0f, nd = 0.0f;
#pragma unroll
    for (int i = 0; i < D; i++) { ns = fmaf(vs[i], vs[i], ns); nd = fmaf(vd[i], vd[i], nd); }
    float is_ = 1.0f / fmaxf(sqrtf(ns), 1e-12f);
    float id_ = 1.0f / fmaxf(sqrtf(nd), 1e-12f);
#pragma unroll
    for (int i = 0; i < D; i++) { vs[i] *= is_; vd[i] *= id_; }

    // ms = coef * Hs(Hd(xd))
    float dot1 = 0.0f;
#pragma unroll
    for (int i = 0; i < D; i++) dot1 = fmaf(vd[i], xd[i], dot1);
#pragma unroll
    for (int i = 0; i < D; i++) ms[i] = fmaf(-2.0f * dot1, vd[i], xd[i]);
    float dot2 = 0.0f;
#pragma unroll
    for (int i = 0; i < D; i++) dot2 = fmaf(vs[i], ms[i], dot2);
#pragma unroll
    for (int i = 0; i < D; i++) ms[i] = coef * fmaf(-2.0f * dot2, vs[i], ms[i]);

    // md = coef * Hd(Hs(xs))
    float dot3 = 0.0f;
#pragma unroll
    for (int i = 0; i < D; i++) dot3 = fmaf(vs[i], xs[i], dot3);
#pragma unroll
    for (int i = 0; i < D; i++) md[i] = fmaf(-2.0f * dot3, vs[i], xs[i]);
    float dot4 = 0.0f;
#pragma unroll
    for (int i = 0; i < D; i++) dot4 = fmaf(vd[i], md[i], dot4);
#pragma unroll
    for (int i = 0; i < D; i++) md[i] = coef * fmaf(-2.0f * dot4, vd[i], md[i]);
}

// ---------------------------------------------------------------------------
// Weight staging into LDS (shared by both edge kernels)
// ---------------------------------------------------------------------------
__device__ __forceinline__ void stage_weights(
    const void* W1, const void* b1, const void* W2, const void* b2, int f32,
    float* sW1, float* sW2t, float* sb1, float* sb2)
{
    int t = threadIdx.x;
    for (int idx = t; idx < HID * 2 * D; idx += blockDim.x)
        sW1[idx] = ld_f(W1, idx, f32);
    for (int idx = t; idx < HID * D; idx += blockDim.x) {
        int j = idx / D, i = idx % D;
        sW2t[idx] = ld_f(W2, i * HID + j, f32);
    }
    if (t < HID) sb1[t] = ld_f(b1, t, f32);
    if (t < D)  sb2[t] = ld_f(b2, t, f32);
}

// ===========================================================================
// CSR path kernels
// ===========================================================================
__global__ void csr_init_kernel(int* __restrict__ wsI,
                                const void* __restrict__ x,
                                const void* __restrict__ ei) {
    int i = blockIdx.x * blockDim.x + threadIdx.x;
    if (i < N_NODES) wsI[CNT_OFF + i] = 0;
    if (blockIdx.x == 0 && threadIdx.x == 0)
        detect_flags(x, ei, wsI + FLAGS_I);
}

__global__ void csr_count_kernel(const void* __restrict__ ei, int* __restrict__ wsI) {
    int i64 = wsI[FLAGS_I + 1];
    int e = blockIdx.x * blockDim.x + threadIdx.x;
    if (e >= N_EDGES) return;
    int s, d;
    load_edge(ei, e, i64, s, d);
    atomicAdd(&wsI[CNT_OFF + s], 1);
    atomicAdd(&wsI[CNT_OFF + d], 1);
}

__global__ __launch_bounds__(1024) void csr_scan_kernel(int* __restrict__ wsI) {
    __shared__ int sm[1024];
    int t = threadIdx.x;
    const int CH = (N_NODES + 1023) / 1024;   // 49
    int beg = t * CH;
    int end = min(beg + CH, N_NODES);
    const int* cnt = wsI + CNT_OFF;
    int* off = wsI + OFF_OFF;
    int* cur = wsI + CUR_OFF;
    int s = 0;
    for (int i = beg; i < end; i++) s += cnt[i];
    sm[t] = s;
    __syncthreads();
    for (int st = 1; st < 1024; st <<= 1) {
        int v = (t >= st) ? sm[t - st] : 0;
        __syncthreads();
        sm[t] += v;
        __syncthreads();
    }
    int run = sm[t] - s;   // exclusive prefix of this thread's chunk
    for (int i = beg; i < end; i++) {
        off[i] = run;
        cur[i] = run;
        run += cnt[i];
    }
    if (t == 1023) off[N_NODES] = sm[1023];
}

__global__ void csr_fill_kernel(const void* __restrict__ ei, int* __restrict__ wsI) {
    int i64 = wsI[FLAGS_I + 1];
    int e = blockIdx.x * blockDim.x + threadIdx.x;
    if (e >= N_EDGES) return;
    int s, d;
    load_edge(ei, e, i64, s, d);
    int ps = atomicAdd(&wsI[CUR_OFF + s], 1);
    wsI[ITEMS_OFF + ps] = e;             // side 0: msg block e
    int pd = atomicAdd(&wsI[CUR_OFF + d], 1);
    wsI[ITEMS_OFF + pd] = N_EDGES + e;   // side 1: msg block E+e
}

__global__ __launch_bounds__(256) void csr_edge_kernel(
    const void* __restrict__ x,
    const void* __restrict__ ei,
    const void* __restrict__ W1,
    const void* __restrict__ b1,
    const void* __restrict__ W2,
    const void* __restrict__ b2,
    int* __restrict__ wsI)
{
    __shared__ __align__(16) float sW1[HID * 2 * D];
    __shared__ __align__(16) float sW2t[HID * D];
    __shared__ float sb1[HID];
    __shared__ float sb2[D];

    int f32 = wsI[FLAGS_I];
    int i64 = wsI[FLAGS_I + 1];
    stage_weights(W1, b1, W2, b2, f32, sW1, sW2t, sb1, sb2);
    __syncthreads();

    int e = blockIdx.x * blockDim.x + threadIdx.x;
    if (e >= N_EDGES) return;

    int s, d;
    load_edge(ei, e, i64, s, d);

    float xs[D], xd[D];
    load16(x, (long long)s * D, f32, xs);
    load16(x, (long long)d * D, f32, xd);

    float degs = (float)wsI[CNT_OFF + s];
    float degd = (float)wsI[CNT_OFF + d];
    float coef = (1.0f / sqrtf(fmaxf(degs, 1e-5f))) * (1.0f / sqrtf(fmaxf(degd, 1e-5f)));

    float ms[D], md[D];
    edge_math(sW1, sW2t, sb1, sb2, xs, xd, coef, ms, md);

    float* msg = (float*)(wsI + MSG_OFF);
    float4* m0 = (float4*)(msg + (long long)e * D);
    m0[0] = make_float4(ms[0], ms[1], ms[2], ms[3]);
    m0[1] = make_float4(ms[4], ms[5], ms[6], ms[7]);
    m0[2] = make_float4(ms[8], ms[9], ms[10], ms[11]);
    m0[3] = make_float4(ms[12], ms[13], ms[14], ms[15]);
    float4* m1 = (float4*)(msg + (long long)(N_EDGES + e) * D);
    m1[0] = make_float4(md[0], md[1], md[2], md[3]);
    m1[1] = make_float4(md[4], md[5], md[6], md[7]);
    m1[2] = make_float4(md[8], md[9], md[10], md[11]);
    m1[3] = make_float4(md[12], md[13], md[14], md[15]);
}

// 16 lanes per node; lane i sums dim i over the node's incident messages.
__global__ __launch_bounds__(256) void csr_gather_kernel(
    const void* __restrict__ x,
    const int* __restrict__ wsI,
    void* __restrict__ out)
{
    int f32 = wsI[FLAGS_I];
    int n = blockIdx.x * 16 + (threadIdx.x >> 4);
    int i = threadIdx.x & 15;
    if (n >= N_NODES) return;

    const int* off = wsI + OFF_OFF;
    const int* items = wsI + ITEMS_OFF;
    const float* msg = (const float*)(wsI + MSG_OFF);

    int beg = off[n], end = off[n + 1];
    float a = 0.0f;
    for (int it = beg; it < end; it++) {
        int blk = items[it];                      // broadcast read across 16 lanes
        a += msg[(long long)blk * D + i];         // 64B coalesced per 16-lane group
    }
    float v = ld_f(x, n * D + i, f32) + a;
    v = fmaxf(v, 0.0f);
    if (f32) ((float*)out)[n * D + i] = v;
    else     ((__hip_bfloat16*)out)[n * D + i] = __float2bfloat16(v);
}

// ===========================================================================
// Fallback path (R3 structure, known-good): float atomics into acc
// ===========================================================================
__global__ void fb_init_kernel(float* __restrict__ ws,
                               const void* __restrict__ x,
                               const void* __restrict__ ei) {
    int i = blockIdx.x * blockDim.x + threadIdx.x;
    if (i < FB_FLAGS) ws[i] = 0.0f;
    if (blockIdx.x == 0 && threadIdx.x == 0)
        detect_flags(x, ei, (int*)(ws + FB_FLAGS));
}

__global__ void fb_deg_kernel(const void* __restrict__ ei, float* __restrict__ ws) {
    int i64 = ((const int*)(ws + FB_FLAGS))[1];
    int e = blockIdx.x * blockDim.x + threadIdx.x;
    if (e >= N_EDGES) return;
    int s, d;
    load_edge(ei, e, i64, s, d);
    atomicAdd(&ws[s], 1.0f);
    atomicAdd(&ws[d], 1.0f);
}

__global__ __launch_bounds__(256) void fb_edge_kernel(
    const void* __restrict__ x,
    const void* __restrict__ ei,
    const void* __restrict__ W1,
    const void* __restrict__ b1,
    const void* __restrict__ W2,
    const void* __restrict__ b2,
    float* __restrict__ ws)
{
    __shared__ __align__(16) float sW1[HID * 2 * D];
    __shared__ __align__(16) float sW2t[HID * D];
    __shared__ float sb1[HID];
    __shared__ float sb2[D];

    const int* flags = (const int*)(ws + FB_FLAGS);
    int f32 = flags[0];
    int i64 = flags[1];
    stage_weights(W1, b1, W2, b2, f32, sW1, sW2t, sb1, sb2);
    __syncthreads();

    int e = blockIdx.x * blockDim.x + threadIdx.x;
    if (e >= N_EDGES) return;

    int s, d;
    load_edge(ei, e, i64, s, d);

    float xs[D], xd[D];
    load16(x, (long long)s * D, f32, xs);
    load16(x, (long long)d * D, f32, xd);

    float coef = (1.0f / sqrtf(fmaxf(ws[s], 1e-5f))) * (1.0f / sqrtf(fmaxf(ws[d], 1e-5f)));

    float ms[D], md[D];
    edge_math(sW1, sW2t, sb1, sb2, xs, xd, coef, ms, md);

    float* acc = ws + FB_NDEG;
#pragma unroll
    for (int i = 0; i < D; i++) atomicAdd(&acc[(long long)s * D + i], ms[i]);
#pragma unroll
    for (int i = 0; i < D; i++) atomicAdd(&acc[(long long)d * D + i], md[i]);
}

__global__ void fb_finalize_kernel(const void* __restrict__ x,
                                   const float* __restrict__ ws,
                                   void* __restrict__ out)
{
    int f32 = ((const int*)(ws + FB_FLAGS))[0];
    const float* acc = ws + FB_NDEG;
    int i = blockIdx.x * blockDim.x + threadIdx.x;
    if (i >= FB_NACC) return;
    float v = ld_f(x, i, f32) + acc[i];
    v = fmaxf(v, 0.0f);
    if (f32) ((float*)out)[i] = v;
    else     ((__hip_bfloat16*)out)[i] = __float2bfloat16(v);
}

// ===========================================================================
extern "C" void kernel_launch(void* const* d_in, const int* in_sizes, int n_in,
                              void* d_out, int out_size, void* d_ws, size_t ws_size,
                              hipStream_t stream)
{
    const void* x  = d_in[0];
    const void* ei = d_in[1];
    const void* W1 = d_in[2];
    const void* b1 = d_in[3];
    const void* W2 = d_in[4];
    const void* b2 = d_in[5];

    int blk = 256;
    if (ws_size >= CSR_NEEDED_BYTES) {
        int* wsI = (int*)d_ws;
        csr_init_kernel<<<(N_NODES + blk - 1) / blk, blk, 0, stream>>>(wsI, x, ei);
        csr_count_kernel<<<(N_EDGES + blk - 1) / blk, blk, 0, stream>>>(ei, wsI);
        csr_scan_kernel<<<1, 1024, 0, stream>>>(wsI);
        csr_fill_kernel<<<(N_EDGES + blk - 1) / blk, blk, 0, stream>>>(ei, wsI);
        csr_edge_kernel<<<(N_EDGES + blk - 1) / blk, blk, 0, stream>>>(x, ei, W1, b1, W2, b2, wsI);
        csr_gather_kernel<<<(N_NODES + 15) / 16, blk, 0, stream>>>(x, wsI, d_out);
    } else {
        float* ws = (float*)d_ws;
        fb_init_kernel<<<(FB_FLAGS + blk - 1) / blk, blk, 0, stream>>>(ws, x, ei);
        fb_deg_kernel<<<(N_EDGES + blk - 1) / blk, blk, 0, stream>>>(ei, ws);
        fb_edge_kernel<<<(N_EDGES + blk - 1) / blk, blk, 0, stream>>>(x, ei, W1, b1, W2, b2, ws);
        fb_finalize_kernel<<<(FB_NACC + blk - 1) / blk, blk, 0, stream>>>(x, ws, d_out);
    }
}

// Round 5
// 209.668 us; speedup vs baseline: 3.7785x; 1.7412x over previous
//
#include <hip/hip_runtime.h>
#include <hip/hip_bf16.h>

#define N_NODES 50000
#define N_EDGES 400000
#define D 16
#define HID 64

#define SCAN_B 256
#define SCAN_G ((N_NODES + SCAN_B - 1) / SCAN_B)   // 196

// ---------------- int-indexed workspace layout (CSR path) ----------------
#define CNT_OFF   0                         // [N] int degree counts
#define OFF_OFF   (N_NODES)                 // [N+1] int CSR offsets
#define CUR_OFF   (2 * N_NODES + 1)         // [N] int fill cursors
#define BS_OFF    (3 * N_NODES + 1)         // [SCAN_B] block sums
#define BS2_OFF   (BS_OFF + SCAN_B)         // [SCAN_B] block exclusive offsets
#define FLAGS_I   (BS2_OFF + SCAN_B)        // [2] dtype flags
#define MSG_OFF   ((FLAGS_I + 2 + 3) & ~3)  // [2E*16] float msgs, 16B-aligned
#define CSR_NEEDED_BYTES ((size_t)(MSG_OFF + 2 * N_EDGES * D) * 4 + 64)

// ---------------- fallback (atomic) layout ----------------
#define FB_NDEG   (N_NODES)
#define FB_NACC   (N_NODES * D)
#define FB_FLAGS  (FB_NDEG + FB_NACC)

// ---------------------------------------------------------------------------
// dtype helpers — harness may hand us bf16 or fp32 floats, int32 or int64
// indices. Detect from data device-side (branch-uniform, ~free).
// ---------------------------------------------------------------------------
__device__ __forceinline__ float bf_bits(unsigned short us) {
    return __uint_as_float(((unsigned)us) << 16);
}

__device__ __forceinline__ float ld_f(const void* p, int idx, int f32) {
    return f32 ? ((const float*)p)[idx]
               : bf_bits(((const unsigned short*)p)[idx]);
}

__device__ __forceinline__ void load16(const void* __restrict__ p, long long base,
                                       int f32, float* o) {
    if (f32) {
        const float4* q = (const float4*)((const float*)p + base);
        float4 a = q[0], b = q[1], c = q[2], d = q[3];
        o[0]=a.x; o[1]=a.y; o[2]=a.z; o[3]=a.w;
        o[4]=b.x; o[5]=b.y; o[6]=b.z; o[7]=b.w;
        o[8]=c.x; o[9]=c.y; o[10]=c.z; o[11]=c.w;
        o[12]=d.x; o[13]=d.y; o[14]=d.z; o[15]=d.w;
    } else {
        const uint4* q = (const uint4*)((const unsigned short*)p + base);
        uint4 a = q[0], b = q[1];
        unsigned u[8] = {a.x, a.y, a.z, a.w, b.x, b.y, b.z, b.w};
#pragma unroll
        for (int k = 0; k < 8; k++) {
            o[2 * k]     = __uint_as_float(u[k] << 16);
            o[2 * k + 1] = __uint_as_float(u[k] & 0xffff0000u);
        }
    }
}

__device__ __forceinline__ void load_edge(const void* __restrict__ ei, int e, int is64,
                                          int& s, int& d) {
    if (is64) {
        const long long* p = (const long long*)ei;
        s = (int)p[e];
        d = (int)p[N_EDGES + e];
    } else {
        const int* p = (const int*)ei;
        s = p[e];
        d = p[N_EDGES + e];
    }
}

__device__ __forceinline__ void detect_flags(const void* x, const void* ei, int* flags) {
    const unsigned short* h = (const unsigned short*)x;
    int f32 = 0;
    for (int k = 0; k < 256; k++) {
        float v = bf_bits(h[k]);
        if (!(v == v) || fabsf(v) > 1.0e6f) { f32 = 1; break; }
    }
    const long long* p = (const long long*)ei;
    int i64 = 1;
    for (int k = 0; k < 16; k++) {
        long long v = p[k];
        if (v < 0 || v >= N_NODES) { i64 = 0; break; }
    }
    flags[0] = f32;
    flags[1] = i64;
}

// ---------------------------------------------------------------------------
// Shared per-edge math: ms = coef*Hs(Hd(xd)), md = coef*Hd(Hs(xs))
// ---------------------------------------------------------------------------
__device__ __forceinline__ void edge_math(
    const float* __restrict__ sW1, const float* __restrict__ sW2t,
    const float* __restrict__ sb1, const float* __restrict__ sb2,
    const float* xs, const float* xd, float coef,
    float* ms, float* md)
{
    float vs[D], vd[D];
#pragma unroll
    for (int i = 0; i < D; i++) { vs[i] = sb2[i]; vd[i] = sb2[i]; }

#pragma unroll 4
    for (int j = 0; j < HID; j++) {
        float hs = sb1[j], hd = sb1[j];
        const float* w = &sW1[j * 2 * D];
#pragma unroll
        for (int k = 0; k < D; k++) {
            float w0 = w[k];
            float w1 = w[D + k];
            hs = fmaf(w0, xs[k], hs);
            hs = fmaf(w1, xd[k], hs);
            hd = fmaf(w0, xd[k], hd);
            hd = fmaf(w1, xs[k], hd);
        }
        hs = fmaxf(hs, 0.0f);
        hd = fmaxf(hd, 0.0f);
        const float* w2 = &sW2t[j * D];
#pragma unroll
        for (int i = 0; i < D; i++) {
            vs[i] = fmaf(w2[i], hs, vs[i]);
            vd[i] = fmaf(w2[i], hd, vd[i]);
        }
    }

    float ns = 0.0f, nd = 0.0f;
#pragma unroll
    for (int i = 0; i < D; i++) { ns = fmaf(vs[i], vs[i], ns); nd = fmaf(vd[i], vd[i], nd); }
    float is_ = 1.0f / fmaxf(sqrtf(ns), 1e-12f);
    float id_ = 1.0f / fmaxf(sqrtf(nd), 1e-12f);
#pragma unroll
    for (int i = 0; i < D; i++) { vs[i] *= is_; vd[i] *= id_; }

    float dot1 = 0.0f;
#pragma unroll
    for (int i = 0; i < D; i++) dot1 = fmaf(vd[i], xd[i], dot1);
#pragma unroll
    for (int i = 0; i < D; i++) ms[i] = fmaf(-2.0f * dot1, vd[i], xd[i]);
    float dot2 = 0.0f;
#pragma unroll
    for (int i = 0; i < D; i++) dot2 = fmaf(vs[i], ms[i], dot2);
#pragma unroll
    for (int i = 0; i < D; i++) ms[i] = coef * fmaf(-2.0f * dot2, vs[i], ms[i]);

    float dot3 = 0.0f;
#pragma unroll
    for (int i = 0; i < D; i++) dot3 = fmaf(vs[i], xs[i], dot3);
#pragma unroll
    for (int i = 0; i < D; i++) md[i] = fmaf(-2.0f * dot3, vs[i], xs[i]);
    float dot4 = 0.0f;
#pragma unroll
    for (int i = 0; i < D; i++) dot4 = fmaf(vd[i], md[i], dot4);
#pragma unroll
    for (int i = 0; i < D; i++) md[i] = coef * fmaf(-2.0f * dot4, vd[i], md[i]);
}

__device__ __forceinline__ void stage_weights(
    const void* W1, const void* b1, const void* W2, const void* b2, int f32,
    float* sW1, float* sW2t, float* sb1, float* sb2)
{
    int t = threadIdx.x;
    for (int idx = t; idx < HID * 2 * D; idx += blockDim.x)
        sW1[idx] = ld_f(W1, idx, f32);
    for (int idx = t; idx < HID * D; idx += blockDim.x) {
        int j = idx / D, i = idx % D;
        sW2t[idx] = ld_f(W2, i * HID + j, f32);
    }
    if (t < HID) sb1[t] = ld_f(b1, t, f32);
    if (t < D)  sb2[t] = ld_f(b2, t, f32);
}

// ===========================================================================
// CSR path kernels
// ===========================================================================
__global__ void csr_init_kernel(int* __restrict__ wsI,
                                const void* __restrict__ x,
                                const void* __restrict__ ei) {
    int i = blockIdx.x * blockDim.x + threadIdx.x;
    if (i < N_NODES) wsI[CNT_OFF + i] = 0;
    if (blockIdx.x == 0 && threadIdx.x == 0)
        detect_flags(x, ei, wsI + FLAGS_I);
}

__global__ void csr_count_kernel(const void* __restrict__ ei, int* __restrict__ wsI) {
    int i64 = wsI[FLAGS_I + 1];
    int e = blockIdx.x * blockDim.x + threadIdx.x;
    if (e >= N_EDGES) return;
    int s, d;
    load_edge(ei, e, i64, s, d);
    atomicAdd(&wsI[CNT_OFF + s], 1);
    atomicAdd(&wsI[CNT_OFF + d], 1);
}

// --- hierarchical scan: 196 blocks x 256 ---
__global__ __launch_bounds__(SCAN_B) void csr_scan1_kernel(int* __restrict__ wsI) {
    __shared__ int sm[SCAN_B];
    int t = threadIdx.x;
    int g = blockIdx.x * SCAN_B + t;
    int c = (g < N_NODES) ? wsI[CNT_OFF + g] : 0;
    sm[t] = c;
    __syncthreads();
    for (int st = SCAN_B / 2; st > 0; st >>= 1) {
        if (t < st) sm[t] += sm[t + st];
        __syncthreads();
    }
    if (t == 0) wsI[BS_OFF + blockIdx.x] = sm[0];
}

__global__ __launch_bounds__(SCAN_B) void csr_scan2_kernel(int* __restrict__ wsI) {
    __shared__ int sm[SCAN_B];
    int t = threadIdx.x;
    int v = (t < SCAN_G) ? wsI[BS_OFF + t] : 0;
    sm[t] = v;
    __syncthreads();
    for (int st = 1; st < SCAN_B; st <<= 1) {
        int u = (t >= st) ? sm[t - st] : 0;
        __syncthreads();
        sm[t] += u;
        __syncthreads();
    }
    if (t < SCAN_G) wsI[BS2_OFF + t] = sm[t] - v;   // exclusive
}

__global__ __launch_bounds__(SCAN_B) void csr_scan3_kernel(int* __restrict__ wsI) {
    __shared__ int sm[SCAN_B];
    int t = threadIdx.x;
    int g = blockIdx.x * SCAN_B + t;
    int c = (g < N_NODES) ? wsI[CNT_OFF + g] : 0;
    sm[t] = c;
    __syncthreads();
    for (int st = 1; st < SCAN_B; st <<= 1) {
        int u = (t >= st) ? sm[t - st] : 0;
        __syncthreads();
        sm[t] += u;
        __syncthreads();
    }
    int excl = sm[t] - c + wsI[BS2_OFF + blockIdx.x];
    if (g < N_NODES) {
        wsI[OFF_OFF + g] = excl;
        wsI[CUR_OFF + g] = excl;
        if (g == N_NODES - 1) wsI[OFF_OFF + N_NODES] = excl + c;
    }
}

// Edge kernel: computes both messages, claims node-grouped slots directly.
__global__ __launch_bounds__(256) void csr_edge_kernel(
    const void* __restrict__ x,
    const void* __restrict__ ei,
    const void* __restrict__ W1,
    const void* __restrict__ b1,
    const void* __restrict__ W2,
    const void* __restrict__ b2,
    int* __restrict__ wsI)
{
    __shared__ __align__(16) float sW1[HID * 2 * D];
    __shared__ __align__(16) float sW2t[HID * D];
    __shared__ float sb1[HID];
    __shared__ float sb2[D];

    int f32 = wsI[FLAGS_I];
    int i64 = wsI[FLAGS_I + 1];
    stage_weights(W1, b1, W2, b2, f32, sW1, sW2t, sb1, sb2);
    __syncthreads();

    int e = blockIdx.x * blockDim.x + threadIdx.x;
    if (e >= N_EDGES) return;

    int s, d;
    load_edge(ei, e, i64, s, d);

    float xs[D], xd[D];
    load16(x, (long long)s * D, f32, xs);
    load16(x, (long long)d * D, f32, xd);

    float degs = (float)wsI[CNT_OFF + s];
    float degd = (float)wsI[CNT_OFF + d];
    float coef = (1.0f / sqrtf(fmaxf(degs, 1e-5f))) * (1.0f / sqrtf(fmaxf(degd, 1e-5f)));

    float ms[D], md[D];
    edge_math(sW1, sW2t, sb1, sb2, xs, xd, coef, ms, md);

    float* msg = (float*)(wsI + MSG_OFF);
    int slot_s = atomicAdd(&wsI[CUR_OFF + s], 1);
    float4* m0 = (float4*)(msg + (long long)slot_s * D);
    m0[0] = make_float4(ms[0], ms[1], ms[2], ms[3]);
    m0[1] = make_float4(ms[4], ms[5], ms[6], ms[7]);
    m0[2] = make_float4(ms[8], ms[9], ms[10], ms[11]);
    m0[3] = make_float4(ms[12], ms[13], ms[14], ms[15]);
    int slot_d = atomicAdd(&wsI[CUR_OFF + d], 1);
    float4* m1 = (float4*)(msg + (long long)slot_d * D);
    m1[0] = make_float4(md[0], md[1], md[2], md[3]);
    m1[1] = make_float4(md[4], md[5], md[6], md[7]);
    m1[2] = make_float4(md[8], md[9], md[10], md[11]);
    m1[3] = make_float4(md[12], md[13], md[14], md[15]);
}

// 16 lanes per node; lane i sums dim i over the node's contiguous msg range.
__global__ __launch_bounds__(256) void csr_gather_kernel(
    const void* __restrict__ x,
    const int* __restrict__ wsI,
    void* __restrict__ out)
{
    int f32 = wsI[FLAGS_I];
    int n = blockIdx.x * 16 + (threadIdx.x >> 4);
    int i = threadIdx.x & 15;
    if (n >= N_NODES) return;

    const int* off = wsI + OFF_OFF;
    const float* msg = (const float*)(wsI + MSG_OFF);

    int beg = off[n], end = off[n + 1];
    float a = 0.0f;
    for (int it = beg; it < end; it++)
        a += msg[(long long)it * D + i];          // fully contiguous per node
    float v = ld_f(x, n * D + i, f32) + a;
    v = fmaxf(v, 0.0f);
    if (f32) ((float*)out)[n * D + i] = v;
    else     ((__hip_bfloat16*)out)[n * D + i] = __float2bfloat16(v);
}

// ===========================================================================
// Fallback path (R3 structure, known-good): float atomics into acc
// ===========================================================================
__global__ void fb_init_kernel(float* __restrict__ ws,
                               const void* __restrict__ x,
                               const void* __restrict__ ei) {
    int i = blockIdx.x * blockDim.x + threadIdx.x;
    if (i < FB_FLAGS) ws[i] = 0.0f;
    if (blockIdx.x == 0 && threadIdx.x == 0)
        detect_flags(x, ei, (int*)(ws + FB_FLAGS));
}

__global__ void fb_deg_kernel(const void* __restrict__ ei, float* __restrict__ ws) {
    int i64 = ((const int*)(ws + FB_FLAGS))[1];
    int e = blockIdx.x * blockDim.x + threadIdx.x;
    if (e >= N_EDGES) return;
    int s, d;
    load_edge(ei, e, i64, s, d);
    atomicAdd(&ws[s], 1.0f);
    atomicAdd(&ws[d], 1.0f);
}

__global__ __launch_bounds__(256) void fb_edge_kernel(
    const void* __restrict__ x,
    const void* __restrict__ ei,
    const void* __restrict__ W1,
    const void* __restrict__ b1,
    const void* __restrict__ W2,
    const void* __restrict__ b2,
    float* __restrict__ ws)
{
    __shared__ __align__(16) float sW1[HID * 2 * D];
    __shared__ __align__(16) float sW2t[HID * D];
    __shared__ float sb1[HID];
    __shared__ float sb2[D];

    const int* flags = (const int*)(ws + FB_FLAGS);
    int f32 = flags[0];
    int i64 = flags[1];
    stage_weights(W1, b1, W2, b2, f32, sW1, sW2t, sb1, sb2);
    __syncthreads();

    int e = blockIdx.x * blockDim.x + threadIdx.x;
    if (e >= N_EDGES) return;

    int s, d;
    load_edge(ei, e, i64, s, d);

    float xs[D], xd[D];
    load16(x, (long long)s * D, f32, xs);
    load16(x, (long long)d * D, f32, xd);

    float coef = (1.0f / sqrtf(fmaxf(ws[s], 1e-5f))) * (1.0f / sqrtf(fmaxf(ws[d], 1e-5f)));

    float ms[D], md[D];
    edge_math(sW1, sW2t, sb1, sb2, xs, xd, coef, ms, md);

    float* acc = ws + FB_NDEG;
#pragma unroll
    for (int i = 0; i < D; i++) atomicAdd(&acc[(long long)s * D + i], ms[i]);
#pragma unroll
    for (int i = 0; i < D; i++) atomicAdd(&acc[(long long)d * D + i], md[i]);
}

__global__ void fb_finalize_kernel(const void* __restrict__ x,
                                   const float* __restrict__ ws,
                                   void* __restrict__ out)
{
    int f32 = ((const int*)(ws + FB_FLAGS))[0];
    const float* acc = ws + FB_NDEG;
    int i = blockIdx.x * blockDim.x + threadIdx.x;
    if (i >= FB_NACC) return;
    float v = ld_f(x, i, f32) + acc[i];
    v = fmaxf(v, 0.0f);
    if (f32) ((float*)out)[i] = v;
    else     ((__hip_bfloat16*)out)[i] = __float2bfloat16(v);
}

// ===========================================================================
extern "C" void kernel_launch(void* const* d_in, const int* in_sizes, int n_in,
                              void* d_out, int out_size, void* d_ws, size_t ws_size,
                              hipStream_t stream)
{
    const void* x  = d_in[0];
    const void* ei = d_in[1];
    const void* W1 = d_in[2];
    const void* b1 = d_in[3];
    const void* W2 = d_in[4];
    const void* b2 = d_in[5];

    int blk = 256;
    if (ws_size >= CSR_NEEDED_BYTES) {
        int* wsI = (int*)d_ws;
        csr_init_kernel<<<(N_NODES + blk - 1) / blk, blk, 0, stream>>>(wsI, x, ei);
        csr_count_kernel<<<(N_EDGES + blk - 1) / blk, blk, 0, stream>>>(ei, wsI);
        csr_scan1_kernel<<<SCAN_G, SCAN_B, 0, stream>>>(wsI);
        csr_scan2_kernel<<<1, SCAN_B, 0, stream>>>(wsI);
        csr_scan3_kernel<<<SCAN_G, SCAN_B, 0, stream>>>(wsI);
        csr_edge_kernel<<<(N_EDGES + blk - 1) / blk, blk, 0, stream>>>(x, ei, W1, b1, W2, b2, wsI);
        csr_gather_kernel<<<(N_NODES + 15) / 16, blk, 0, stream>>>(x, wsI, d_out);
    } else {
        float* ws = (float*)d_ws;
        fb_init_kernel<<<(FB_FLAGS + blk - 1) / blk, blk, 0, stream>>>(ws, x, ei);
        fb_deg_kernel<<<(N_EDGES + blk - 1) / blk, blk, 0, stream>>>(ei, ws);
        fb_edge_kernel<<<(N_EDGES + blk - 1) / blk, blk, 0, stream>>>(x, ei, W1, b1, W2, b2, ws);
        fb_finalize_kernel<<<(FB_NACC + blk - 1) / blk, blk, 0, stream>>>(x, ws, d_out);
    }
}